// Round 2
// 550.063 us; speedup vs baseline: 1.0562x; 1.0562x over previous
//
#include <hip/hip_runtime.h>

#define BB 8
#define NN 16384
#define DIMD 512
#define MVV 8
#define SCALE_C 0.1f
#define EPS_C 1e-5f

typedef unsigned int u32;
typedef float f32x4 __attribute__((ext_vector_type(4)));

// load 8 contiguous fp32 (16B aligned) -> 8 fp32
__device__ __forceinline__ void load8f(const float* __restrict__ p, float* f) {
    float4 a = *(const float4*)p;
    float4 b = *(const float4*)(p + 4);
    f[0] = a.x; f[1] = a.y; f[2] = a.z; f[3] = a.w;
    f[4] = b.x; f[5] = b.y; f[6] = b.z; f[7] = b.w;
}

__global__ __launch_bounds__(256) void kzero(float* __restrict__ p, int n) {
    int i = blockIdx.x * 256 + threadIdx.x;
    if (i < n) p[i] = 0.0f;
}

// Pass 1: column sums of x over N, per batch. grid (128, 8), block 256.
__global__ __launch_bounds__(256) void kmean(const float* __restrict__ x, float* __restrict__ wsum) {
    const int b = blockIdx.y;
    const int chunk = blockIdx.x;           // 0..127
    const int t = threadIdx.x;
    const int c = t & 63;                   // d-chunk (8 d's)
    const int rt = t >> 6;                  // wave id 0..3
    const int rowsPerBlock = NN / 128;      // 128
    const long base = ((long)b * NN + (long)chunk * rowsPerBlock) * DIMD;

    float acc[8];
#pragma unroll
    for (int j = 0; j < 8; j++) acc[j] = 0.0f;

    // two rows per iteration -> 4 load8f in flight per wave
    for (int r = rt; r < rowsPerBlock; r += 8) {
        const float* p0 = x + base + (long)r * DIMD + c * 8;
        const float* p1 = p0 + 4L * DIMD;
        float f0[8], f1[8];
        load8f(p0, f0);
        load8f(p1, f1);
#pragma unroll
        for (int j = 0; j < 8; j++) acc[j] += f0[j] + f1[j];
    }

    __shared__ float red[256][9];  // +1 pad against bank conflicts
#pragma unroll
    for (int j = 0; j < 8; j++) red[t][j] = acc[j];
    __syncthreads();

    if (t < 64) {
        float s[8];
#pragma unroll
        for (int j = 0; j < 8; j++)
            s[j] = red[t][j] + red[t + 64][j] + red[t + 128][j] + red[t + 192][j];
        float* dst = wsum + b * DIMD + t * 8;
#pragma unroll
        for (int j = 0; j < 8; j++) atomicAdd(dst + j, s[j]);
    }
}

// Pass 2: fold mean-field through Cayley into per-batch WoT[d][i], c2[d].
// grid 8 (one block per b), block 64 (one wave).
__global__ __launch_bounds__(64) void kfold(const float* __restrict__ wsum,
                                            const float* __restrict__ Wm,
                                            const float* __restrict__ bm,
                                            const float* __restrict__ Wo,
                                            const float* __restrict__ bo,
                                            const float* __restrict__ bp,
                                            float* __restrict__ wot,
                                            float* __restrict__ c2) {
    const int b = blockIdx.x;
    const int l = threadIdx.x;
    const float invN = 1.0f / (float)NN;

    float m[8];
#pragma unroll
    for (int j = 0; j < 8; j++) m[j] = wsum[b * DIMD + l * 8 + j] * invN;

    // mf[i] = dot(mean_field, Wm[i,:]) + bm[i], broadcast via butterfly
    float mf[8];
#pragma unroll
    for (int i = 0; i < 8; i++) {
        float wmr[8];
        load8f(Wm + i * DIMD + l * 8, wmr);
        float p = 0.0f;
#pragma unroll
        for (int j = 0; j < 8; j++) p += m[j] * wmr[j];
#pragma unroll
        for (int off = 32; off >= 1; off >>= 1) p += __shfl_xor(p, off, 64);
        mf[i] = p + bm[i];
    }

    // T[i][k] = sum_j C[i,j,k] * mf[j]  (C has exactly one j per (i,k))
    const int masks[8] = {0, 1, 2, 4, 3, 5, 6, 7};
    const int invm[8]  = {0, 1, 2, 4, 3, 5, 6, 7};  // mask -> index
    float T[8][8];
#pragma unroll
    for (int i = 0; i < 8; i++) {
#pragma unroll
        for (int k = 0; k < 8; k++) {
            int bmask = masks[i] ^ masks[k];
            int j = invm[bmask];
            int s = 0, aa = masks[i] >> 1;
            while (aa) { s += __popc(aa & bmask); aa >>= 1; }
            T[i][k] = (s & 1) ? -mf[j] : mf[j];
        }
    }

    // cvec[k] = sum_i bp[i] * T[i][k]
    float cv[8];
#pragma unroll
    for (int k = 0; k < 8; k++) {
        float s = 0.0f;
#pragma unroll
        for (int i = 0; i < 8; i++) s += bp[i] * T[i][k];
        cv[k] = s;
    }

    // per-lane: 8 rows d = l*8 + j
#pragma unroll
    for (int j = 0; j < 8; j++) {
        int d = l * 8 + j;
        float wor[8];
        load8f(Wo + d * 8, wor);  // Wo[d][k], contiguous
        float cc = bo[d];
#pragma unroll
        for (int k = 0; k < 8; k++) cc += cv[k] * wor[k];
        c2[b * DIMD + d] = cc;
#pragma unroll
        for (int i = 0; i < 8; i++) {
            float s = 0.0f;
#pragma unroll
            for (int k = 0; k < 8; k++) s += T[i][k] * wor[k];
            wot[((long)b * DIMD + d) * 8 + i] = s;
        }
    }
}

// Pass 3: main streaming pass. One wave per token; lane l owns d in [8l, 8l+8).
// grid (128, 8), block 256 (4 waves).
// v2: software prefetch of next row; reduce-scatter (7 shfl) + cross-group
// allreduce (3 shfl) + readlane broadcast instead of 48-shfl butterfly;
// paired 7-shfl LayerNorm reduction; nontemporal output stores.
__global__ __launch_bounds__(256, 2) void kmain(const float* __restrict__ x,
                                                const float* __restrict__ Wp,
                                                const float* __restrict__ gamma,
                                                const float* __restrict__ beta,
                                                const float* __restrict__ wot,
                                                const float* __restrict__ c2,
                                                float* __restrict__ out) {
    const int b = blockIdx.y;
    const int chunk = blockIdx.x;            // 0..127
    const int w = threadIdx.x >> 6;          // wave 0..3
    const int l = threadIdx.x & 63;
    const int d0 = l * 8;
    const bool b5 = (l & 32) != 0;
    const bool b4 = (l & 16) != 0;
    const bool b3 = (l & 8) != 0;

    // persistent per-lane weights
    float wp[8][8];
#pragma unroll
    for (int i = 0; i < 8; i++) load8f(Wp + i * DIMD + d0, wp[i]);

    float wo[8][8];  // wo[j][i] = WoT[b, d0+j, i]
    const float* wotp = wot + ((long)b * DIMD + d0) * 8;
#pragma unroll
    for (int j = 0; j < 8; j++)
#pragma unroll
        for (int i = 0; i < 8; i++) wo[j][i] = wotp[j * 8 + i];

    float cc[8];
#pragma unroll
    for (int j = 0; j < 8; j++) cc[j] = c2[b * DIMD + d0 + j];

    float g[8], be[8];
    load8f(gamma + d0, g);
    load8f(beta + d0, be);

    const int rowsPerBlock = NN / 128;       // 128
    const long rowbase = (long)b * NN + (long)chunk * rowsPerBlock;

    // prime the pipeline: load first row
    float xv[8];
    load8f(x + (rowbase + w) * DIMD + d0, xv);

    for (int r = w; r < rowsPerBlock; r += 4) {
        // issue next row's load before the compute phase (latency hiding)
        float xn[8];
        const int rn = r + 4;
        if (rn < rowsPerBlock) {
            load8f(x + (rowbase + rn) * DIMD + d0, xn);
        }

        // pm[i] partial = sum over my 8 d's
        float pm[8];
#pragma unroll
        for (int i = 0; i < 8; i++) {
            float p = xv[0] * wp[i][0];
#pragma unroll
            for (int j = 1; j < 8; j++) p += xv[j] * wp[i][j];
            pm[i] = p;
        }

        // reduce-scatter: lane bits 5,4,3 pick value bits 2,1,0 (7 shfl)
        float k1[4];
#pragma unroll
        for (int j = 0; j < 4; j++) {
            float send = b5 ? pm[j] : pm[j + 4];
            float recv = __shfl_xor(send, 32, 64);
            k1[j] = (b5 ? pm[j + 4] : pm[j]) + recv;
        }
        float k2[2];
#pragma unroll
        for (int j = 0; j < 2; j++) {
            float send = b4 ? k1[j] : k1[j + 2];
            float recv = __shfl_xor(send, 16, 64);
            k2[j] = (b4 ? k1[j + 2] : k1[j]) + recv;
        }
        float tsend = b3 ? k2[0] : k2[1];
        float trecv = __shfl_xor(tsend, 8, 64);
        float t = (b3 ? k2[1] : k2[0]) + trecv;
        // t = pm[(l>>3)&7] summed over the 8 lanes sharing l&7.
        // cross-group allreduce over lane bits 2..0 (3 shfl)
        t += __shfl_xor(t, 4, 64);
        t += __shfl_xor(t, 2, 64);
        t += __shfl_xor(t, 1, 64);
        // now every lane holds the full pm[(l>>3)&7]; broadcast via readlane
        float pmt[8];
#pragma unroll
        for (int i = 0; i < 8; i++) pmt[i] = __shfl(t, i << 3, 64);

        float yv[8], s1 = 0.0f, s2 = 0.0f;
#pragma unroll
        for (int j = 0; j < 8; j++) {
            float o = cc[j];
#pragma unroll
            for (int i = 0; i < 8; i++) o += pmt[i] * wo[j][i];
            float y = xv[j] + SCALE_C * o;
            yv[j] = y;
            s1 += y;
            s2 += y * y;
        }

        // paired LN reduction: s1 on bit5=0 lanes, s2 on bit5=1 lanes (7 shfl)
        float lsend = b5 ? s1 : s2;
        float v = (b5 ? s2 : s1) + __shfl_xor(lsend, 32, 64);
        v += __shfl_xor(v, 16, 64);
        v += __shfl_xor(v, 8, 64);
        v += __shfl_xor(v, 4, 64);
        v += __shfl_xor(v, 2, 64);
        v += __shfl_xor(v, 1, 64);
        float vw = __shfl_xor(v, 32, 64);
        float S1 = b5 ? vw : v;
        float S2 = b5 ? v : vw;

        float mu = S1 * (1.0f / DIMD);
        float var = S2 * (1.0f / DIMD) - mu * mu;
        float rs = rsqrtf(var + EPS_C);

        float* po = out + (rowbase + r) * DIMD + d0;
        f32x4 o1 = { g[0] * (yv[0] - mu) * rs + be[0],
                     g[1] * (yv[1] - mu) * rs + be[1],
                     g[2] * (yv[2] - mu) * rs + be[2],
                     g[3] * (yv[3] - mu) * rs + be[3] };
        f32x4 o2 = { g[4] * (yv[4] - mu) * rs + be[4],
                     g[5] * (yv[5] - mu) * rs + be[5],
                     g[6] * (yv[6] - mu) * rs + be[6],
                     g[7] * (yv[7] - mu) * rs + be[7] };
        // nontemporal: keep the 256 MiB out-stream from evicting x in L3
        __builtin_nontemporal_store(o1, (f32x4*)po);
        __builtin_nontemporal_store(o2, (f32x4*)(po + 4));

        // rotate prefetched row in
#pragma unroll
        for (int j = 0; j < 8; j++) xv[j] = xn[j];
    }
}

extern "C" void kernel_launch(void* const* d_in, const int* in_sizes, int n_in,
                              void* d_out, int out_size, void* d_ws, size_t ws_size,
                              hipStream_t stream) {
    const float* x     = (const float*)d_in[0];
    const float* Wp    = (const float*)d_in[1];
    const float* bp    = (const float*)d_in[2];
    const float* Wm    = (const float*)d_in[3];
    const float* bm    = (const float*)d_in[4];
    const float* Wo    = (const float*)d_in[5];
    const float* bo    = (const float*)d_in[6];
    const float* gamma = (const float*)d_in[7];
    const float* beta  = (const float*)d_in[8];

    float* ws   = (float*)d_ws;
    float* wsum = ws;                 // 4096 floats
    float* wot  = ws + 4096;          // 32768 floats
    float* c2   = ws + 4096 + 32768;  // 4096 floats

    kzero<<<16, 256, 0, stream>>>(wsum, BB * DIMD);
    kmean<<<dim3(128, 8), 256, 0, stream>>>(x, wsum);
    kfold<<<8, 64, 0, stream>>>(wsum, Wm, bm, Wo, bo, bp, wot, c2);
    kmain<<<dim3(128, 8), 256, 0, stream>>>(x, Wp, gamma, beta, wot, c2, (float*)d_out);
}

// Round 3
// 526.872 us; speedup vs baseline: 1.1027x; 1.0440x over previous
//
#include <hip/hip_runtime.h>

#define BB 8
#define NN 16384
#define DIMD 512
#define MVV 8
#define SCALE_C 0.1f
#define EPS_C 1e-5f

typedef unsigned int u32;
typedef float f32x4 __attribute__((ext_vector_type(4)));

// load 8 contiguous fp32 (16B aligned) -> 8 fp32
__device__ __forceinline__ void load8f(const float* __restrict__ p, float* f) {
    float4 a = *(const float4*)p;
    float4 b = *(const float4*)(p + 4);
    f[0] = a.x; f[1] = a.y; f[2] = a.z; f[3] = a.w;
    f[4] = b.x; f[5] = b.y; f[6] = b.z; f[7] = b.w;
}

__global__ __launch_bounds__(256) void kzero(float* __restrict__ p, int n) {
    int i = blockIdx.x * 256 + threadIdx.x;
    if (i < n) p[i] = 0.0f;
}

// Pass 1: column sums of x over N, per batch. grid (128, 8), block 256.
// 4 rows per iteration -> 128 B/lane outstanding.
__global__ __launch_bounds__(256) void kmean(const float* __restrict__ x, float* __restrict__ wsum) {
    const int b = blockIdx.y;
    const int chunk = blockIdx.x;           // 0..127
    const int t = threadIdx.x;
    const int c = t & 63;                   // d-chunk (8 d's)
    const int rt = t >> 6;                  // wave id 0..3
    const int rowsPerBlock = NN / 128;      // 128
    const long base = ((long)b * NN + (long)chunk * rowsPerBlock) * DIMD;

    float acc[8];
#pragma unroll
    for (int j = 0; j < 8; j++) acc[j] = 0.0f;

    for (int r = rt; r < rowsPerBlock; r += 16) {
        const float* p0 = x + base + (long)r * DIMD + c * 8;
        float f0[8], f1[8], f2[8], f3[8];
        load8f(p0, f0);
        load8f(p0 + 4L * DIMD, f1);
        load8f(p0 + 8L * DIMD, f2);
        load8f(p0 + 12L * DIMD, f3);
#pragma unroll
        for (int j = 0; j < 8; j++) acc[j] += (f0[j] + f1[j]) + (f2[j] + f3[j]);
    }

    __shared__ float red[256][9];  // +1 pad against bank conflicts
#pragma unroll
    for (int j = 0; j < 8; j++) red[t][j] = acc[j];
    __syncthreads();

    if (t < 64) {
        float s[8];
#pragma unroll
        for (int j = 0; j < 8; j++)
            s[j] = red[t][j] + red[t + 64][j] + red[t + 128][j] + red[t + 192][j];
        float* dst = wsum + b * DIMD + t * 8;
#pragma unroll
        for (int j = 0; j < 8; j++) atomicAdd(dst + j, s[j]);
    }
}

// Pass 2: fold mean-field through Cayley into per-batch WoT[d][i], c2[d].
// grid 8 (one block per b), block 64 (one wave).
__global__ __launch_bounds__(64) void kfold(const float* __restrict__ wsum,
                                            const float* __restrict__ Wm,
                                            const float* __restrict__ bm,
                                            const float* __restrict__ Wo,
                                            const float* __restrict__ bo,
                                            const float* __restrict__ bp,
                                            float* __restrict__ wot,
                                            float* __restrict__ c2) {
    const int b = blockIdx.x;
    const int l = threadIdx.x;
    const float invN = 1.0f / (float)NN;

    float m[8];
#pragma unroll
    for (int j = 0; j < 8; j++) m[j] = wsum[b * DIMD + l * 8 + j] * invN;

    // mf[i] = dot(mean_field, Wm[i,:]) + bm[i], broadcast via butterfly
    float mf[8];
#pragma unroll
    for (int i = 0; i < 8; i++) {
        float wmr[8];
        load8f(Wm + i * DIMD + l * 8, wmr);
        float p = 0.0f;
#pragma unroll
        for (int j = 0; j < 8; j++) p += m[j] * wmr[j];
#pragma unroll
        for (int off = 32; off >= 1; off >>= 1) p += __shfl_xor(p, off, 64);
        mf[i] = p + bm[i];
    }

    // T[i][k] = sum_j C[i,j,k] * mf[j]  (C has exactly one j per (i,k))
    const int masks[8] = {0, 1, 2, 4, 3, 5, 6, 7};
    const int invm[8]  = {0, 1, 2, 4, 3, 5, 6, 7};  // mask -> index
    float T[8][8];
#pragma unroll
    for (int i = 0; i < 8; i++) {
#pragma unroll
        for (int k = 0; k < 8; k++) {
            int bmask = masks[i] ^ masks[k];
            int j = invm[bmask];
            int s = 0, aa = masks[i] >> 1;
            while (aa) { s += __popc(aa & bmask); aa >>= 1; }
            T[i][k] = (s & 1) ? -mf[j] : mf[j];
        }
    }

    // cvec[k] = sum_i bp[i] * T[i][k]
    float cv[8];
#pragma unroll
    for (int k = 0; k < 8; k++) {
        float s = 0.0f;
#pragma unroll
        for (int i = 0; i < 8; i++) s += bp[i] * T[i][k];
        cv[k] = s;
    }

    // per-lane: 8 rows d = l*8 + j
#pragma unroll
    for (int j = 0; j < 8; j++) {
        int d = l * 8 + j;
        float wor[8];
        load8f(Wo + d * 8, wor);  // Wo[d][k], contiguous
        float cc = bo[d];
#pragma unroll
        for (int k = 0; k < 8; k++) cc += cv[k] * wor[k];
        c2[b * DIMD + d] = cc;
#pragma unroll
        for (int i = 0; i < 8; i++) {
            float s = 0.0f;
#pragma unroll
            for (int k = 0; k < 8; k++) s += T[i][k] * wor[k];
            wot[((long)b * DIMD + d) * 8 + i] = s;
        }
    }
}

// Pass 3: main streaming pass. One wave per token-pair; lane l owns d in [8l, 8l+8).
// grid (128, 8), block 256 (4 waves).
// v3: TWO rows per wave processed phase-interleaved (doubles independent
// shuffle chains -> halves dependency stalls); reverse row traversal so the
// exactly-L3-sized x stream is re-read MRU-first; nontemporal out stores.
__global__ __launch_bounds__(256, 2) void kmain(const float* __restrict__ x,
                                                const float* __restrict__ Wp,
                                                const float* __restrict__ gamma,
                                                const float* __restrict__ beta,
                                                const float* __restrict__ wot,
                                                const float* __restrict__ c2,
                                                float* __restrict__ out) {
    const int b = blockIdx.y;
    const int chunk = blockIdx.x;            // 0..127
    const int w = threadIdx.x >> 6;          // wave 0..3
    const int l = threadIdx.x & 63;
    const int d0 = l * 8;
    const bool b5 = (l & 32) != 0;
    const bool b4 = (l & 16) != 0;
    const bool b3 = (l & 8) != 0;

    // persistent per-lane weights
    float wp[8][8];
#pragma unroll
    for (int i = 0; i < 8; i++) load8f(Wp + i * DIMD + d0, wp[i]);

    float wo[8][8];  // wo[j][i] = WoT[b, d0+j, i]
    const float* wotp = wot + ((long)b * DIMD + d0) * 8;
#pragma unroll
    for (int j = 0; j < 8; j++)
#pragma unroll
        for (int i = 0; i < 8; i++) wo[j][i] = wotp[j * 8 + i];

    float cc[8];
#pragma unroll
    for (int j = 0; j < 8; j++) cc[j] = c2[b * DIMD + d0 + j];

    float g[8], be[8];
    load8f(gamma + d0, g);
    load8f(beta + d0, be);

    const long rowbase = (long)b * NN + (long)chunk * 128;

    // wave w owns rows {2w, 2w+1} + 8k; traverse k = 15 -> 0.
    float xv[2][8];
    {
        const int r = 2 * w + 8 * 15;
        load8f(x + (rowbase + r) * DIMD + d0, xv[0]);
        load8f(x + (rowbase + r + 1) * DIMD + d0, xv[1]);
    }

    for (int k = 15; k >= 0; k--) {
        const int r = 2 * w + 8 * k;

        // prefetch next pair (latency hiding)
        float xn[2][8];
        if (k > 0) {
            load8f(x + (rowbase + r - 8) * DIMD + d0, xn[0]);
            load8f(x + (rowbase + r - 7) * DIMD + d0, xn[1]);
        }

        // pm[u][i] partial = sum over my 8 d's
        float pm[2][8];
#pragma unroll
        for (int u = 0; u < 2; u++)
#pragma unroll
            for (int i = 0; i < 8; i++) {
                float p = xv[u][0] * wp[i][0];
#pragma unroll
                for (int j = 1; j < 8; j++) p += xv[u][j] * wp[i][j];
                pm[u][i] = p;
            }

        // reduce-scatter: lane bits 5,4,3 pick value bits 2,1,0 (7 shfl/row,
        // both rows interleaved level-by-level)
        float k1[2][4];
#pragma unroll
        for (int u = 0; u < 2; u++)
#pragma unroll
            for (int j = 0; j < 4; j++) {
                float send = b5 ? pm[u][j] : pm[u][j + 4];
                float recv = __shfl_xor(send, 32, 64);
                k1[u][j] = (b5 ? pm[u][j + 4] : pm[u][j]) + recv;
            }
        float k2[2][2];
#pragma unroll
        for (int u = 0; u < 2; u++)
#pragma unroll
            for (int j = 0; j < 2; j++) {
                float send = b4 ? k1[u][j] : k1[u][j + 2];
                float recv = __shfl_xor(send, 16, 64);
                k2[u][j] = (b4 ? k1[u][j + 2] : k1[u][j]) + recv;
            }
        float t[2];
#pragma unroll
        for (int u = 0; u < 2; u++) {
            float ts = b3 ? k2[u][0] : k2[u][1];
            float tr = __shfl_xor(ts, 8, 64);
            t[u] = (b3 ? k2[u][1] : k2[u][0]) + tr;
        }
        // cross-group allreduce over lane bits 2..0 (3 levels, rows interleaved)
#pragma unroll
        for (int u = 0; u < 2; u++) t[u] += __shfl_xor(t[u], 4, 64);
#pragma unroll
        for (int u = 0; u < 2; u++) t[u] += __shfl_xor(t[u], 2, 64);
#pragma unroll
        for (int u = 0; u < 2; u++) t[u] += __shfl_xor(t[u], 1, 64);
        // broadcast pm[(l>>3)&7] to all lanes
        float pmt[2][8];
#pragma unroll
        for (int u = 0; u < 2; u++)
#pragma unroll
            for (int i = 0; i < 8; i++) pmt[u][i] = __shfl(t[u], i << 3, 64);

        float yv[2][8], s1[2], s2[2];
#pragma unroll
        for (int u = 0; u < 2; u++) {
            s1[u] = 0.0f; s2[u] = 0.0f;
#pragma unroll
            for (int j = 0; j < 8; j++) {
                float o = cc[j];
#pragma unroll
                for (int i = 0; i < 8; i++) o += pmt[u][i] * wo[j][i];
                float y = xv[u][j] + SCALE_C * o;
                yv[u][j] = y;
                s1[u] += y;
                s2[u] += y * y;
            }
        }

        // paired LN reduction: s1 on bit5=0 lanes, s2 on bit5=1 (rows interleaved)
        float v[2];
#pragma unroll
        for (int u = 0; u < 2; u++) {
            float ls = b5 ? s1[u] : s2[u];
            v[u] = (b5 ? s2[u] : s1[u]) + __shfl_xor(ls, 32, 64);
        }
#pragma unroll
        for (int u = 0; u < 2; u++) v[u] += __shfl_xor(v[u], 16, 64);
#pragma unroll
        for (int u = 0; u < 2; u++) v[u] += __shfl_xor(v[u], 8, 64);
#pragma unroll
        for (int u = 0; u < 2; u++) v[u] += __shfl_xor(v[u], 4, 64);
#pragma unroll
        for (int u = 0; u < 2; u++) v[u] += __shfl_xor(v[u], 2, 64);
#pragma unroll
        for (int u = 0; u < 2; u++) v[u] += __shfl_xor(v[u], 1, 64);

#pragma unroll
        for (int u = 0; u < 2; u++) {
            float vw = __shfl_xor(v[u], 32, 64);
            float S1 = b5 ? vw : v[u];
            float S2 = b5 ? v[u] : vw;
            float mu = S1 * (1.0f / DIMD);
            float var = S2 * (1.0f / DIMD) - mu * mu;
            float rs = rsqrtf(var + EPS_C);

            float* po = out + (rowbase + r + u) * DIMD + d0;
            f32x4 o1 = { g[0] * (yv[u][0] - mu) * rs + be[0],
                         g[1] * (yv[u][1] - mu) * rs + be[1],
                         g[2] * (yv[u][2] - mu) * rs + be[2],
                         g[3] * (yv[u][3] - mu) * rs + be[3] };
            f32x4 o2 = { g[4] * (yv[u][4] - mu) * rs + be[4],
                         g[5] * (yv[u][5] - mu) * rs + be[5],
                         g[6] * (yv[u][6] - mu) * rs + be[6],
                         g[7] * (yv[u][7] - mu) * rs + be[7] };
            // nontemporal: keep the out-stream from evicting x in L3
            __builtin_nontemporal_store(o1, (f32x4*)po);
            __builtin_nontemporal_store(o2, (f32x4*)(po + 4));
        }

        // rotate prefetched pair in
#pragma unroll
        for (int u = 0; u < 2; u++)
#pragma unroll
            for (int j = 0; j < 8; j++) xv[u][j] = xn[u][j];
    }
}

extern "C" void kernel_launch(void* const* d_in, const int* in_sizes, int n_in,
                              void* d_out, int out_size, void* d_ws, size_t ws_size,
                              hipStream_t stream) {
    const float* x     = (const float*)d_in[0];
    const float* Wp    = (const float*)d_in[1];
    const float* bp    = (const float*)d_in[2];
    const float* Wm    = (const float*)d_in[3];
    const float* bm    = (const float*)d_in[4];
    const float* Wo    = (const float*)d_in[5];
    const float* bo    = (const float*)d_in[6];
    const float* gamma = (const float*)d_in[7];
    const float* beta  = (const float*)d_in[8];

    float* ws   = (float*)d_ws;
    float* wsum = ws;                 // 4096 floats
    float* wot  = ws + 4096;          // 32768 floats
    float* c2   = ws + 4096 + 32768;  // 4096 floats

    kzero<<<16, 256, 0, stream>>>(wsum, BB * DIMD);
    kmean<<<dim3(128, 8), 256, 0, stream>>>(x, wsum);
    kfold<<<8, 64, 0, stream>>>(wsum, Wm, bm, Wo, bo, bp, wot, c2);
    kmain<<<dim3(128, 8), 256, 0, stream>>>(x, Wp, gamma, beta, wot, c2, (float*)d_out);
}